// Round 1
// baseline (2674.800 us; speedup 1.0000x reference)
//
#include <hip/hip_runtime.h>
#include <stdint.h>

typedef __bf16 bf16;
typedef __bf16 bf16x8 __attribute__((ext_vector_type(8)));
typedef float  f32x4  __attribute__((ext_vector_type(4)));

// problem dims
#define NBLK 32           // blocks per (dir,stage) in recurrence
// ws layout (bytes)
#define OFF_CTR    0
#define CTR_BYTES  (4*128*4)
#define OFF_HIST   2048
#define HIST_ONE   (128*32*256*2)            // 2 MB per hist (128 slots of [32][256] bf16)
#define OFF_H0F    (OFF_HIST)
#define OFF_H0B    (OFF_HIST + 1*HIST_ONE)
#define OFF_H1F    (OFF_HIST + 2*HIST_ONE)
#define OFF_H1B    (OFF_HIST + 3*HIST_ONE)
#define OFF_XF     (OFF_HIST + 4*HIST_ONE)   // 8,390,656
#define XF_BYTES   (4064*256*2)
#define OFF_XB     (OFF_XF + XF_BYTES)
#define OFF_FW0T   (OFF_XB + XF_BYTES)
#define W0T_BYTES  (1024*256*2)
#define OFF_BW0T   (OFF_FW0T + W0T_BYTES)
#define OFF_PRE0F  (OFF_BW0T + W0T_BYTES)
#define PRE_BYTES  (4064*1024*4)
#define OFF_PRE0B  (OFF_PRE0F + PRE_BYTES)
#define OFF_WPT    (OFF_PRE0B + PRE_BYTES)
#define WPT_BYTES  (32000*512*2)
#define OFF_CTX    (OFF_WPT + WPT_BYTES)
#define CTX_BYTES  (4032*512*2)
#define OFF_MF     (OFF_CTX + CTX_BYTES)
#define OFF_MB     (OFF_MF + 4096)
#define ZERO_BYTES OFF_XF                    // ctr + all hist slot-0s (zero everything, 8.4MB)

__device__ __forceinline__ int swz8(int row, int kblk) { return (kblk ^ (row & 7)) << 3; }

// ---------------- embedding gather + masks (builds xf/xb bf16, t-major) ----------------
__global__ __launch_bounds__(256) void embed_kernel(
    const int* __restrict__ x, const float* __restrict__ tab,
    bf16* __restrict__ xf, bf16* __restrict__ xb,
    unsigned char* __restrict__ mf, unsigned char* __restrict__ mb)
{
  int t = blockIdx.x;      // 0..126
  int b = blockIdx.y;      // 0..31
  int k = threadIdx.x;     // 0..255
  int tokf = x[b*128 + t];          // fwd consumes token t
  int tokb = x[b*128 + 127 - t];    // bwd step s=t consumes token 127-t
  xf[(size_t)(t*32+b)*256 + k] = (bf16)tab[(size_t)tokf*256 + k];
  xb[(size_t)(t*32+b)*256 + k] = (bf16)tab[(size_t)tokb*256 + k];
  if (k == 0) { mf[t*32+b] = (tokf != 0); mb[t*32+b] = (tokb != 0); }
}

// ---------------- f32 [R][C] -> bf16 [C][R] transpose ----------------
__global__ __launch_bounds__(256) void transpose_to_bf16(
    const float* __restrict__ in, bf16* __restrict__ out, int R, int C)
{
  __shared__ float tile[64][65];
  int c0 = blockIdx.x*64, r0 = blockIdx.y*64;
  int tid = threadIdx.x;
  int r = tid >> 2, cs = (tid & 3)*16;
  #pragma unroll
  for (int i = 0; i < 16; i += 4) {
    float4 v = *(const float4*)(in + (size_t)(r0+r)*C + c0 + cs + i);
    tile[r][cs+i+0]=v.x; tile[r][cs+i+1]=v.y; tile[r][cs+i+2]=v.z; tile[r][cs+i+3]=v.w;
  }
  __syncthreads();
  int c = tid >> 2, rs = (tid & 3)*16;
  #pragma unroll
  for (int i = 0; i < 16; ++i)
    out[(size_t)(c0+c)*R + r0 + rs + i] = (bf16)tile[rs+i][c];
}

// ---------------- bf16 MFMA GEMM: C[M][N] = A[M][K] * BT[N][K]^T + bias[N] ----------------
// BM=128 BN=128 BK=64. N%128==0, K%64==0, M guarded.
__global__ __launch_bounds__(256) void gemm_bf16(
    const bf16* __restrict__ A, const bf16* __restrict__ BT,
    const float* __restrict__ bias, float* __restrict__ C,
    int M, int N, int K)
{
  __shared__ bf16 As[128][72];
  __shared__ bf16 Bs[128][72];
  int tid = threadIdx.x;
  int row0 = blockIdx.x*128, col0 = blockIdx.y*128;
  int wave = tid >> 6, lane = tid & 63, l15 = lane & 15, quad = lane >> 4;
  int wm = (wave & 1)*64, wn = (wave >> 1)*64;
  f32x4 acc[4][4] = {};
  for (int kk = 0; kk < K; kk += 64) {
    #pragma unroll
    for (int i = 0; i < 4; ++i) {
      int o = i*256 + tid;            // 1024 octs of 8 bf16
      int r = o >> 3, seg = o & 7;
      int gr = row0 + r;
      if (gr < M) *(uint4*)&As[r][seg*8] = *(const uint4*)(A + (size_t)gr*K + kk + seg*8);
      else        *(uint4*)&As[r][seg*8] = make_uint4(0,0,0,0);
      *(uint4*)&Bs[r][seg*8] = *(const uint4*)(BT + (size_t)(col0 + r)*K + kk + seg*8);
    }
    __syncthreads();
    #pragma unroll
    for (int ks = 0; ks < 64; ks += 32) {
      bf16x8 af[4], bfr[4];
      #pragma unroll
      for (int mi = 0; mi < 4; ++mi) af[mi]  = *(const bf16x8*)&As[wm + mi*16 + l15][ks + quad*8];
      #pragma unroll
      for (int ni = 0; ni < 4; ++ni) bfr[ni] = *(const bf16x8*)&Bs[wn + ni*16 + l15][ks + quad*8];
      #pragma unroll
      for (int mi = 0; mi < 4; ++mi)
        #pragma unroll
        for (int ni = 0; ni < 4; ++ni)
          acc[mi][ni] = __builtin_amdgcn_mfma_f32_16x16x32_bf16(af[mi], bfr[ni], acc[mi][ni], 0, 0, 0);
    }
    __syncthreads();
  }
  #pragma unroll
  for (int ni = 0; ni < 4; ++ni) {
    int col = col0 + wn + ni*16 + l15;
    float bv = bias[col];
    #pragma unroll
    for (int mi = 0; mi < 4; ++mi) {
      int rbase = row0 + wm + mi*16 + quad*4;
      #pragma unroll
      for (int r = 0; r < 4; ++r) {
        int grow = rbase + r;
        if (grow < M) C[(size_t)grow*N + col] = acc[mi][ni][r] + bv;
      }
    }
  }
}

// ---------------- persistent pipelined LSTM recurrence ----------------
// grid = 128 blocks: dir(2) x stage(2) x NBLK(32). Each block owns 8 hidden units.
// stage0: z = pre0[t] + h0 @ U0 ; stage1: z = [h0(t);h1(t-1)] @ [W1;U1] + b1
// h histories in global (bf16, [slot][b][k], slot = t+1, slot0 = zeros).
// cross-block handoff: store h -> __syncthreads (drains vmcnt) -> tid0 __threadfence (wbl2)
// -> agent-scope release atomicAdd; consumer: agent acquire spin + __threadfence (inv).
__global__ __launch_bounds__(256) void recur_kernel(
    const float* __restrict__ pre0f, const float* __restrict__ pre0b,
    const float* __restrict__ fU0, const float* __restrict__ bU0,
    const float* __restrict__ fW1, const float* __restrict__ fU1,
    const float* __restrict__ bW1, const float* __restrict__ bU1,
    const float* __restrict__ fb1, const float* __restrict__ bb1,
    const unsigned char* __restrict__ mf, const unsigned char* __restrict__ mb,
    bf16* __restrict__ h0f, bf16* __restrict__ h0b,
    bf16* __restrict__ h1f, bf16* __restrict__ h1b,
    int* __restrict__ ctr)
{
  __shared__ bf16 U_T[32][512];   // [z-col][k], k-blocks swizzled by (col&7)
  __shared__ bf16 hA[32][512];    // [b][k], k-blocks swizzled by (b&7); first 4224B aliased as z_s
  float (*z_s)[33] = (float (*)[33])hA;

  int tid = threadIdx.x;
  int bx = blockIdx.x;
  int dir = bx >> 6, rest = bx & 63, stage = rest >> 5, blk = rest & 31;
  int j0 = blk * 8;
  const float* pre = dir ? pre0b : pre0f;
  const unsigned char* mgl = dir ? mb : mf;
  bf16* h0 = dir ? h0b : h0f;
  bf16* h1 = dir ? h1b : h1f;
  const int K = stage ? 512 : 256;
  int* c0 = ctr + (dir*2 + 0)*128;
  int* c1 = ctr + (dir*2 + 1)*128;

  // ---- one-time: load weight slice into LDS (bf16, transposed [col][k]) ----
  if (stage == 0) {
    const float* U = dir ? bU0 : fU0;
    for (int idx = tid; idx < 32*256; idx += 256) {
      int c = idx >> 8, k = idx & 255;
      int u = c >> 2, g = c & 3;
      U_T[c][swz8(c, k >> 3) | (k & 7)] = (bf16)U[(size_t)k*1024 + g*256 + j0 + u];
    }
  } else {
    const float* W = dir ? bW1 : fW1;
    const float* U = dir ? bU1 : fU1;
    for (int idx = tid; idx < 32*512; idx += 256) {
      int c = idx >> 9, k = idx & 511;
      int u = c >> 2, g = c & 3;
      int gc = g*256 + j0 + u;
      float v = (k < 256) ? W[(size_t)k*1024 + gc] : U[(size_t)(k-256)*1024 + gc];
      U_T[c][swz8(c, k >> 3) | (k & 7)] = (bf16)v;
    }
  }
  int gb = tid & 31, gu = tid >> 5;        // gate thread: batch gb, unit j0+gu
  float c_state = 0.f, h_state = 0.f;
  float bi = 0.f, bff = 0.f, bgg = 0.f, boo = 0.f;
  if (stage == 1) {
    const float* bias = dir ? bb1 : fb1;
    bi  = bias[0*256 + j0 + gu];
    bff = bias[1*256 + j0 + gu];
    bgg = bias[2*256 + j0 + gu];
    boo = bias[3*256 + j0 + gu];
  }
  int wave = tid >> 6, lane = tid & 63, l15 = lane & 15, quad = lane >> 4;
  int m0 = (wave & 1)*16, n0 = (wave >> 1)*16;
  __syncthreads();

  for (int t = 0; t < 127; ++t) {
    // prefetch step-constant operands (no dependency on handoff)
    float p_i = bi, p_f = bff, p_g = bgg, p_o = boo;
    if (stage == 0) {
      const float* p = pre + ((size_t)t*32 + gb)*1024 + j0 + gu;
      p_i = p[0]; p_f = p[256]; p_g = p[512]; p_o = p[768];
    }
    unsigned char msk = mgl[t*32 + gb];

    // [A] wait for producers
    if (tid == 0) {
      int spins;
      if (stage == 0) {
        if (t > 0) { spins = 0;
          while (__hip_atomic_load(&c0[t-1], __ATOMIC_ACQUIRE, __HIP_MEMORY_SCOPE_AGENT) < NBLK)
            { if (++spins > (1<<18)) break; __builtin_amdgcn_s_sleep(1); } }
      } else {
        spins = 0;
        while (__hip_atomic_load(&c0[t], __ATOMIC_ACQUIRE, __HIP_MEMORY_SCOPE_AGENT) < NBLK)
          { if (++spins > (1<<18)) break; __builtin_amdgcn_s_sleep(1); }
        if (t > 0) { spins = 0;
          while (__hip_atomic_load(&c1[t-1], __ATOMIC_ACQUIRE, __HIP_MEMORY_SCOPE_AGENT) < NBLK)
            { if (++spins > (1<<18)) break; __builtin_amdgcn_s_sleep(1); } }
      }
      __threadfence();   // acquire: invalidate stale L1/L2 before h loads
    }
    __syncthreads();

    // [B] load hA from global hist
    if (stage == 0) {
      const bf16* src = h0 + (size_t)t*8192;   // h0(t-1) at slot t
      #pragma unroll
      for (int i = 0; i < 4; ++i) {
        int o = i*256 + tid;                   // 1024 octs
        int r = o >> 5, seg = o & 31;
        *(uint4*)&hA[r][swz8(r, seg)] = *(const uint4*)(src + r*256 + seg*8);
      }
    } else {
      const bf16* s0p = h0 + (size_t)(t+1)*8192;  // h0(t)
      const bf16* s1p = h1 + (size_t)t*8192;      // h1(t-1)
      #pragma unroll
      for (int i = 0; i < 8; ++i) {
        int o = i*256 + tid;                   // 2048 octs
        int r = o >> 6, seg = o & 63;
        const bf16* sp = (seg < 32) ? (s0p + r*256 + seg*8) : (s1p + r*256 + (seg-32)*8);
        *(uint4*)&hA[r][swz8(r, seg)] = *(const uint4*)sp;
      }
    }
    __syncthreads();

    // MFMA: z[32b][32c] = hA[32][K] * U_T[32c][K]^T
    f32x4 acc = {0.f, 0.f, 0.f, 0.f};
    for (int kc = 0; kc < K; kc += 32) {
      int kb = (kc >> 3) + quad;
      bf16x8 a  = *(const bf16x8*)&hA[m0 + l15][swz8(m0 + l15, kb)];
      bf16x8 bb = *(const bf16x8*)&U_T[n0 + l15][swz8(n0 + l15, kb)];
      acc = __builtin_amdgcn_mfma_f32_16x16x32_bf16(a, bb, acc, 0, 0, 0);
    }
    __syncthreads();   // [C1] all waves done reading hA (z_s aliases it)
    #pragma unroll
    for (int r = 0; r < 4; ++r) z_s[m0 + quad*4 + r][n0 + l15] = acc[r];
    __syncthreads();   // [C2]

    // gates (fp32, Keras order i,f,g,o), persistent c/h state in registers
    float zi = z_s[gb][gu*4+0] + p_i;
    float zf = z_s[gb][gu*4+1] + p_f;
    float zg = z_s[gb][gu*4+2] + p_g;
    float zo = z_s[gb][gu*4+3] + p_o;
    float ig = 1.f/(1.f + expf(-zi));
    float fg = 1.f/(1.f + expf(-zf));
    float gg = tanhf(zg);
    float og = 1.f/(1.f + expf(-zo));
    float cn = fg*c_state + ig*gg;
    float hn = og*tanhf(cn);
    if (msk) { c_state = cn; h_state = hn; }
    bf16* dst = (stage == 0 ? h0 : h1) + (size_t)(t+1)*8192 + gb*256 + j0 + gu;
    *dst = (bf16)h_state;
    __syncthreads();   // [D] drains vmcnt: all h stores in L2
    if (tid == 0) {
      __threadfence(); // release: writeback L2 so other XCDs see h
      __hip_atomic_fetch_add(stage == 0 ? &c0[t] : &c1[t], 1, __ATOMIC_RELEASE, __HIP_MEMORY_SCOPE_AGENT);
    }
    __syncthreads();
  }
}

// ---------------- ctx assembly: ctx[b*126+tau][0:256]=h1f(tau), [256:512]=h1b(tau+1) ----------------
__global__ __launch_bounds__(256) void ctx_kernel(
    const bf16* __restrict__ h1f, const bf16* __restrict__ h1b, bf16* __restrict__ ctx)
{
  int tau = blockIdx.x;   // 0..125
  int b = blockIdx.y;     // 0..31
  int k = threadIdx.x;    // 0..255
  size_t r = (size_t)(b*126 + tau)*512;
  ctx[r + k]       = h1f[(size_t)(tau+1)*8192 + b*256 + k];   // f[b][tau]  -> slot tau+1
  ctx[r + 256 + k] = h1b[(size_t)(tau+2)*8192 + b*256 + k];   // b_out[b][tau+1] -> slot tau+2
}

// ---------------- NSP head: out[b][j] = bn[j] + sum_f ctx[b][f]*Wn[f][j] ----------------
__global__ __launch_bounds__(256) void nsp_kernel(
    const bf16* __restrict__ ctx, const float* __restrict__ Wn,
    const float* __restrict__ bn, float* __restrict__ out)
{
  int b = blockIdx.x, tid = threadIdx.x;
  const unsigned short* cb = (const unsigned short*)ctx;
  float a0 = 0.f, a1 = 0.f;
  for (int flat = tid; flat < 64512; flat += 256) {
    int tau = flat >> 9, k = flat & 511;
    float cv = __uint_as_float((unsigned)cb[(size_t)(b*126 + tau)*512 + k] << 16);
    float2 w = *(const float2*)(Wn + 2*(size_t)flat);
    a0 += cv*w.x; a1 += cv*w.y;
  }
  __shared__ float r0[256], r1[256];
  r0[tid] = a0; r1[tid] = a1;
  __syncthreads();
  for (int s = 128; s > 0; s >>= 1) {
    if (tid < s) { r0[tid] += r0[tid+s]; r1[tid] += r1[tid+s]; }
    __syncthreads();
  }
  if (tid == 0) { out[b*2+0] = r0[0] + bn[0]; out[b*2+1] = r1[0] + bn[1]; }
}

// ---------------- launch ----------------
extern "C" void kernel_launch(void* const* d_in, const int* in_sizes, int n_in,
                              void* d_out, int out_size, void* d_ws, size_t ws_size,
                              hipStream_t stream)
{
  const int*   x   = (const int*)d_in[0];
  const float* tab = (const float*)d_in[1];
  const float* fW  = (const float*)d_in[2];
  const float* fU  = (const float*)d_in[3];
  const float* fb  = (const float*)d_in[4];
  const float* bW  = (const float*)d_in[5];
  const float* bU  = (const float*)d_in[6];
  const float* bb  = (const float*)d_in[7];
  const float* Wp  = (const float*)d_in[8];
  const float* bp  = (const float*)d_in[9];
  const float* Wn  = (const float*)d_in[10];
  const float* bn  = (const float*)d_in[11];
  float* out = (float*)d_out;
  char* ws = (char*)d_ws;

  int*  ctr   = (int*)(ws + OFF_CTR);
  bf16* h0f   = (bf16*)(ws + OFF_H0F);
  bf16* h0b   = (bf16*)(ws + OFF_H0B);
  bf16* h1f   = (bf16*)(ws + OFF_H1F);
  bf16* h1b   = (bf16*)(ws + OFF_H1B);
  bf16* xf    = (bf16*)(ws + OFF_XF);
  bf16* xb    = (bf16*)(ws + OFF_XB);
  bf16* fW0T  = (bf16*)(ws + OFF_FW0T);
  bf16* bW0T  = (bf16*)(ws + OFF_BW0T);
  float* pre0f = (float*)(ws + OFF_PRE0F);
  float* pre0b = (float*)(ws + OFF_PRE0B);
  bf16* WpT   = (bf16*)(ws + OFF_WPT);
  bf16* ctx   = (bf16*)(ws + OFF_CTX);
  unsigned char* mf = (unsigned char*)(ws + OFF_MF);
  unsigned char* mb = (unsigned char*)(ws + OFF_MB);

  // zero counters + hist slot0s (ws is poisoned 0xAA before every call)
  hipMemsetAsync(ws, 0, ZERO_BYTES, stream);

  embed_kernel<<<dim3(127, 32), 256, 0, stream>>>(x, tab, xf, xb, mf, mb);

  transpose_to_bf16<<<dim3(16, 4),  256, 0, stream>>>(fW, fW0T, 256, 1024);
  transpose_to_bf16<<<dim3(16, 4),  256, 0, stream>>>(bW, bW0T, 256, 1024);
  transpose_to_bf16<<<dim3(500, 8), 256, 0, stream>>>(Wp, WpT, 512, 32000);

  // layer-0 input projections (bias folded in)
  gemm_bf16<<<dim3(32, 8), 256, 0, stream>>>(xf, fW0T, fb, pre0f, 4064, 1024, 256);
  gemm_bf16<<<dim3(32, 8), 256, 0, stream>>>(xb, bW0T, bb, pre0b, 4064, 1024, 256);

  // pipelined 2-layer recurrence, both directions
  recur_kernel<<<128, 256, 0, stream>>>(
      pre0f, pre0b,
      fU, bU,
      fW + 262144, fU + 262144, bW + 262144, bU + 262144,
      fb + 1024, bb + 1024,
      mf, mb, h0f, h0b, h1f, h1b, ctr);

  ctx_kernel<<<dim3(126, 32), 256, 0, stream>>>(h1f, h1b, ctx);

  // word logits: [4032,512] x [512,32000] + bp -> d_out
  gemm_bf16<<<dim3(32, 250), 256, 0, stream>>>(ctx, WpT, bp, out, 4032, 32000, 512);

  nsp_kernel<<<32, 256, 0, stream>>>(ctx, Wn, bn, out + (size_t)4032*32000);
}

// Round 2
// 1718.617 us; speedup vs baseline: 1.5564x; 1.5564x over previous
//
#include <hip/hip_runtime.h>
#include <stdint.h>

typedef __bf16 bf16;
typedef __bf16 bf16x8 __attribute__((ext_vector_type(8)));
typedef float  f32x4  __attribute__((ext_vector_type(4)));

// recurrence decomposition: per (dir,stage) NB blocks of 512 threads, 16 units each
#define NB 16
// ws layout (bytes)
#define OFF_CTR    0
#define CTR_BYTES  (4*128*4)
#define OFF_HIST   2048
#define HIST_ONE   (128*32*256*2)            // 2 MB per hist (128 slots of [32][256] bf16)
#define OFF_H0F    (OFF_HIST)
#define OFF_H0B    (OFF_HIST + 1*HIST_ONE)
#define OFF_H1F    (OFF_HIST + 2*HIST_ONE)
#define OFF_H1B    (OFF_HIST + 3*HIST_ONE)
#define OFF_XF     (OFF_HIST + 4*HIST_ONE)   // 8,390,656
#define XF_BYTES   (4064*256*2)
#define OFF_XB     (OFF_XF + XF_BYTES)
#define OFF_FW0T   (OFF_XB + XF_BYTES)
#define W0T_BYTES  (1024*256*2)
#define OFF_BW0T   (OFF_FW0T + W0T_BYTES)
#define OFF_PRE0F  (OFF_BW0T + W0T_BYTES)
#define PRE_BYTES  (4064*1024*4)
#define OFF_PRE0B  (OFF_PRE0F + PRE_BYTES)
#define OFF_WPT    (OFF_PRE0B + PRE_BYTES)
#define WPT_BYTES  (32000*512*2)
#define OFF_CTX    (OFF_WPT + WPT_BYTES)
#define CTX_BYTES  (4032*512*2)
#define OFF_MF     (OFF_CTX + CTX_BYTES)
#define OFF_MB     (OFF_MF + 4096)
#define ZERO_BYTES OFF_XF                    // ctr + all hist (8.4MB)

__device__ __forceinline__ int swz8(int row, int kblk) { return (kblk ^ (row & 7)) << 3; }

// system-scope (MALL-coherent, cache-bypassing) helpers — no L2 flush/inv needed
__device__ __forceinline__ uint64_t sys_load_u64(const uint64_t* p) {
  return __hip_atomic_load(p, __ATOMIC_RELAXED, __HIP_MEMORY_SCOPE_SYSTEM);
}
__device__ __forceinline__ void sys_store_u16(unsigned short* p, unsigned short v) {
  __hip_atomic_store(p, v, __ATOMIC_RELAXED, __HIP_MEMORY_SCOPE_SYSTEM);
}

// ---------------- embedding gather + masks (builds xf/xb bf16, t-major) ----------------
__global__ __launch_bounds__(256) void embed_kernel(
    const int* __restrict__ x, const float* __restrict__ tab,
    bf16* __restrict__ xf, bf16* __restrict__ xb,
    unsigned char* __restrict__ mf, unsigned char* __restrict__ mb)
{
  int t = blockIdx.x;      // 0..126
  int b = blockIdx.y;      // 0..31
  int k = threadIdx.x;     // 0..255
  int tokf = x[b*128 + t];          // fwd consumes token t
  int tokb = x[b*128 + 127 - t];    // bwd step s=t consumes token 127-t
  xf[(size_t)(t*32+b)*256 + k] = (bf16)tab[(size_t)tokf*256 + k];
  xb[(size_t)(t*32+b)*256 + k] = (bf16)tab[(size_t)tokb*256 + k];
  if (k == 0) { mf[t*32+b] = (tokf != 0); mb[t*32+b] = (tokb != 0); }
}

// ---------------- f32 [R][C] -> bf16 [C][R] transpose ----------------
__global__ __launch_bounds__(256) void transpose_to_bf16(
    const float* __restrict__ in, bf16* __restrict__ out, int R, int C)
{
  __shared__ float tile[64][65];
  int c0 = blockIdx.x*64, r0 = blockIdx.y*64;
  int tid = threadIdx.x;
  int r = tid >> 2, cs = (tid & 3)*16;
  #pragma unroll
  for (int i = 0; i < 16; i += 4) {
    float4 v = *(const float4*)(in + (size_t)(r0+r)*C + c0 + cs + i);
    tile[r][cs+i+0]=v.x; tile[r][cs+i+1]=v.y; tile[r][cs+i+2]=v.z; tile[r][cs+i+3]=v.w;
  }
  __syncthreads();
  int c = tid >> 2, rs = (tid & 3)*16;
  #pragma unroll
  for (int i = 0; i < 16; ++i)
    out[(size_t)(c0+c)*R + r0 + rs + i] = (bf16)tile[rs+i][c];
}

// ---------------- bf16 MFMA GEMM: C[M][N] = A[M][K] * BT[N][K]^T + bias[N] ----------------
__global__ __launch_bounds__(256) void gemm_bf16(
    const bf16* __restrict__ A, const bf16* __restrict__ BT,
    const float* __restrict__ bias, float* __restrict__ C,
    int M, int N, int K)
{
  __shared__ bf16 As[128][72];
  __shared__ bf16 Bs[128][72];
  int tid = threadIdx.x;
  int row0 = blockIdx.x*128, col0 = blockIdx.y*128;
  int wave = tid >> 6, lane = tid & 63, l15 = lane & 15, quad = lane >> 4;
  int wm = (wave & 1)*64, wn = (wave >> 1)*64;
  f32x4 acc[4][4] = {};
  for (int kk = 0; kk < K; kk += 64) {
    #pragma unroll
    for (int i = 0; i < 4; ++i) {
      int o = i*256 + tid;            // 1024 octs of 8 bf16
      int r = o >> 3, seg = o & 7;
      int gr = row0 + r;
      if (gr < M) *(uint4*)&As[r][seg*8] = *(const uint4*)(A + (size_t)gr*K + kk + seg*8);
      else        *(uint4*)&As[r][seg*8] = make_uint4(0,0,0,0);
      *(uint4*)&Bs[r][seg*8] = *(const uint4*)(BT + (size_t)(col0 + r)*K + kk + seg*8);
    }
    __syncthreads();
    #pragma unroll
    for (int ks = 0; ks < 64; ks += 32) {
      bf16x8 af[4], bfr[4];
      #pragma unroll
      for (int mi = 0; mi < 4; ++mi) af[mi]  = *(const bf16x8*)&As[wm + mi*16 + l15][ks + quad*8];
      #pragma unroll
      for (int ni = 0; ni < 4; ++ni) bfr[ni] = *(const bf16x8*)&Bs[wn + ni*16 + l15][ks + quad*8];
      #pragma unroll
      for (int mi = 0; mi < 4; ++mi)
        #pragma unroll
        for (int ni = 0; ni < 4; ++ni)
          acc[mi][ni] = __builtin_amdgcn_mfma_f32_16x16x32_bf16(af[mi], bfr[ni], acc[mi][ni], 0, 0, 0);
    }
    __syncthreads();
  }
  #pragma unroll
  for (int ni = 0; ni < 4; ++ni) {
    int col = col0 + wn + ni*16 + l15;
    float bv = bias[col];
    #pragma unroll
    for (int mi = 0; mi < 4; ++mi) {
      int rbase = row0 + wm + mi*16 + quad*4;
      #pragma unroll
      for (int r = 0; r < 4; ++r) {
        int grow = rbase + r;
        if (grow < M) C[(size_t)grow*N + col] = acc[mi][ni][r] + bv;
      }
    }
  }
}

// ---------------- persistent pipelined LSTM recurrence (MALL-coherent handoff) ----------------
// grid = 64 blocks x 512 threads: dir(2) x stage(2) x NB(16). Each block owns 16 units (64 z-cols).
// All h exchange via system-scope (sc0 sc1) loads/stores -> coherent at MALL, NO L2 flush/inv.
// LDS col c (0..63) <-> global z-col (c>>4)*256 + j0 + (c&15)   [gate-major]
__global__ __launch_bounds__(512) void recur_kernel(
    const float* __restrict__ pre0f, const float* __restrict__ pre0b,
    const float* __restrict__ fU0, const float* __restrict__ bU0,
    const float* __restrict__ fW1, const float* __restrict__ fU1,
    const float* __restrict__ bW1, const float* __restrict__ bU1,
    const float* __restrict__ fb1, const float* __restrict__ bb1,
    const unsigned char* __restrict__ mf, const unsigned char* __restrict__ mb,
    bf16* __restrict__ h0f, bf16* __restrict__ h0b,
    bf16* __restrict__ h1f, bf16* __restrict__ h1b,
    int* __restrict__ ctr)
{
  __shared__ bf16 U_T[64][512];   // [lds-col][k], octs swizzled by (col&7)  (64KB)
  __shared__ bf16 hA[32][512];    // [b][k], octs swizzled by (b&7)          (32KB); head aliased as z_s
  float (*z_s)[65] = (float (*)[65])hA;

  int tid = threadIdx.x;
  int bx = blockIdx.x;
  int dir = bx >> 5, stage = (bx >> 4) & 1, blk = bx & 15;
  int j0 = blk * 16;
  const float* pre = dir ? pre0b : pre0f;
  const unsigned char* mgl = dir ? mb : mf;
  bf16* h0 = dir ? h0b : h0f;
  bf16* h1 = dir ? h1b : h1f;
  const int K = stage ? 512 : 256;
  int* c0 = ctr + (dir*2 + 0)*128;
  int* c1 = ctr + (dir*2 + 1)*128;

  // ---- one-time: weight slice -> LDS (bf16, [col][k], k-major loop for coalescing) ----
  if (stage == 0) {
    const float* U = dir ? bU0 : fU0;
    for (int idx = tid; idx < 64*256; idx += 512) {
      int k = idx >> 6, c = idx & 63;
      int gc = (c >> 4)*256 + j0 + (c & 15);
      U_T[c][swz8(c, k >> 3) | (k & 7)] = (bf16)U[(size_t)k*1024 + gc];
    }
  } else {
    const float* W = dir ? bW1 : fW1;
    const float* U = dir ? bU1 : fU1;
    for (int idx = tid; idx < 64*512; idx += 512) {
      int k = idx >> 6, c = idx & 63;
      int gc = (c >> 4)*256 + j0 + (c & 15);
      float v = (k < 256) ? W[(size_t)k*1024 + gc] : U[(size_t)(k-256)*1024 + gc];
      U_T[c][swz8(c, k >> 3) | (k & 7)] = (bf16)v;
    }
  }
  int gb = tid & 31, gu = tid >> 5;        // gate thread: batch gb, unit j0+gu  (gu 0..15)
  float c_state = 0.f, h_state = 0.f;
  float bi = 0.f, bff = 0.f, bgg = 0.f, boo = 0.f;
  if (stage == 1) {
    const float* bias = dir ? bb1 : fb1;
    bi  = bias[0*256 + j0 + gu];
    bff = bias[1*256 + j0 + gu];
    bgg = bias[2*256 + j0 + gu];
    boo = bias[3*256 + j0 + gu];
  }
  int wave = tid >> 6, lane = tid & 63, l15 = lane & 15, quad = lane >> 4;
  int m0 = (wave & 1)*16, n0 = (wave >> 1)*16;     // 2 m-tiles x 4 n-tiles = 8 waves
  __syncthreads();

  for (int t = 0; t < 127; ++t) {
    // step-constant operands (independent of handoff — issue early)
    float p_i = bi, p_f = bff, p_g = bgg, p_o = boo;
    if (stage == 0) {
      const float* p = pre + ((size_t)t*32 + gb)*1024 + j0 + gu;
      p_i = p[0]; p_f = p[256]; p_g = p[512]; p_o = p[768];
    }
    unsigned char msk = mgl[t*32 + gb];

    // [A] wait for producers (relaxed system spins; data path is cache-bypassing so no inv needed)
    if (tid == 0) {
      int spins;
      if (stage == 0) {
        if (t > 0) { spins = 0;
          while (__hip_atomic_load(&c0[t-1], __ATOMIC_RELAXED, __HIP_MEMORY_SCOPE_SYSTEM) < NB)
            { if (++spins > 4096) __builtin_amdgcn_s_sleep(1); if (spins > (1<<18)) break; } }
      } else {
        spins = 0;
        while (__hip_atomic_load(&c0[t], __ATOMIC_RELAXED, __HIP_MEMORY_SCOPE_SYSTEM) < NB)
          { if (++spins > 4096) __builtin_amdgcn_s_sleep(1); if (spins > (1<<18)) break; }
        if (t > 0) { spins = 0;
          while (__hip_atomic_load(&c1[t-1], __ATOMIC_RELAXED, __HIP_MEMORY_SCOPE_SYSTEM) < NB)
            { if (++spins > 4096) __builtin_amdgcn_s_sleep(1); if (spins > (1<<18)) break; } }
      }
      __atomic_signal_fence(__ATOMIC_SEQ_CST);
    }
    __syncthreads();

    // [B] load h into LDS via system-scope 8B loads (read MALL directly)
    if (stage == 0) {
      const uint64_t* src = (const uint64_t*)(h0 + (size_t)t*8192);   // h0(t-1) at slot t
      #pragma unroll
      for (int i = 0; i < 4; ++i) {
        int q = i*512 + tid;                 // 2048 qwords, row r = q>>6 (64 qwords/row)
        int r = q >> 6, seg = q & 63;
        uint64_t v = sys_load_u64(src + q);
        *(uint64_t*)&hA[r][swz8(r, seg >> 1) + (seg & 1)*4] = v;
      }
    } else {
      const uint64_t* s0p = (const uint64_t*)(h0 + (size_t)(t+1)*8192);  // h0(t)
      const uint64_t* s1p = (const uint64_t*)(h1 + (size_t)t*8192);      // h1(t-1)
      #pragma unroll
      for (int i = 0; i < 8; ++i) {
        int q = i*512 + tid;                 // 4096 qwords
        int sel = q >> 11;
        int r = (q >> 6) & 31, seg = q & 63;
        const uint64_t* sp = sel ? s1p : s0p;
        uint64_t v = sys_load_u64(sp + r*64 + seg);
        int oct = (seg >> 1) + sel*32;
        *(uint64_t*)&hA[r][swz8(r, oct) + (seg & 1)*4] = v;
      }
    }
    __syncthreads();

    // MFMA: z[32b][64c] = hA[32][K] * U_T[64c][K]^T   (8 waves: one 16x16 tile each)
    f32x4 acc = {0.f, 0.f, 0.f, 0.f};
    for (int kc = 0; kc < K; kc += 32) {
      int kb = (kc >> 3) + quad;
      bf16x8 a  = *(const bf16x8*)&hA[m0 + l15][swz8(m0 + l15, kb)];
      bf16x8 bb = *(const bf16x8*)&U_T[n0 + l15][swz8(n0 + l15, kb)];
      acc = __builtin_amdgcn_mfma_f32_16x16x32_bf16(a, bb, acc, 0, 0, 0);
    }
    __syncthreads();   // [C1] all waves done reading hA (z_s aliases it)
    #pragma unroll
    for (int r = 0; r < 4; ++r) z_s[m0 + quad*4 + r][n0 + l15] = acc[r];
    __syncthreads();   // [C2]

    // gates (fp32, Keras order i,f,g,o); lds col for (gate g, unit gu) = g*16+gu
    float zi = z_s[gb][ 0 + gu] + p_i;
    float zf = z_s[gb][16 + gu] + p_f;
    float zg = z_s[gb][32 + gu] + p_g;
    float zo = z_s[gb][48 + gu] + p_o;
    float ig = 1.f/(1.f + expf(-zi));
    float fg = 1.f/(1.f + expf(-zf));
    float gg = tanhf(zg);
    float og = 1.f/(1.f + expf(-zo));
    float cn = fg*c_state + ig*gg;
    float hn = og*tanhf(cn);
    if (msk) { c_state = cn; h_state = hn; }

    // store h to MALL (system scope), drain own store, then barrier, then flag
    bf16 hv = (bf16)h_state;
    unsigned short hb;
    __builtin_memcpy(&hb, &hv, 2);
    unsigned short* dst = (unsigned short*)((stage == 0 ? h0 : h1) + (size_t)(t+1)*8192 + gb*256 + j0 + gu);
    sys_store_u16(dst, hb);
    asm volatile("s_waitcnt vmcnt(0)" ::: "memory");
    __syncthreads();   // [D] every thread's store is at the MALL
    if (tid == 0) {
      __atomic_signal_fence(__ATOMIC_SEQ_CST);
      __hip_atomic_fetch_add(stage == 0 ? &c0[t] : &c1[t], 1, __ATOMIC_RELAXED, __HIP_MEMORY_SCOPE_SYSTEM);
    }
    __syncthreads();
  }
}

// ---------------- ctx assembly: ctx[b*126+tau][0:256]=h1f(tau), [256:512]=h1b(tau+1) ----------------
__global__ __launch_bounds__(256) void ctx_kernel(
    const bf16* __restrict__ h1f, const bf16* __restrict__ h1b, bf16* __restrict__ ctx)
{
  int tau = blockIdx.x;   // 0..125
  int b = blockIdx.y;     // 0..31
  int k = threadIdx.x;    // 0..255
  size_t r = (size_t)(b*126 + tau)*512;
  ctx[r + k]       = h1f[(size_t)(tau+1)*8192 + b*256 + k];   // f[b][tau]  -> slot tau+1
  ctx[r + 256 + k] = h1b[(size_t)(tau+2)*8192 + b*256 + k];   // b_out[b][tau+1] -> slot tau+2
}

// ---------------- NSP head ----------------
__global__ __launch_bounds__(256) void nsp_kernel(
    const bf16* __restrict__ ctx, const float* __restrict__ Wn,
    const float* __restrict__ bn, float* __restrict__ out)
{
  int b = blockIdx.x, tid = threadIdx.x;
  const unsigned short* cb = (const unsigned short*)ctx;
  float a0 = 0.f, a1 = 0.f;
  for (int flat = tid; flat < 64512; flat += 256) {
    int tau = flat >> 9, k = flat & 511;
    float cv = __uint_as_float((unsigned)cb[(size_t)(b*126 + tau)*512 + k] << 16);
    float2 w = *(const float2*)(Wn + 2*(size_t)flat);
    a0 += cv*w.x; a1 += cv*w.y;
  }
  __shared__ float r0[256], r1[256];
  r0[tid] = a0; r1[tid] = a1;
  __syncthreads();
  for (int s = 128; s > 0; s >>= 1) {
    if (tid < s) { r0[tid] += r0[tid+s]; r1[tid] += r1[tid+s]; }
    __syncthreads();
  }
  if (tid == 0) { out[b*2+0] = r0[0] + bn[0]; out[b*2+1] = r1[0] + bn[1]; }
}

// ---------------- launch ----------------
extern "C" void kernel_launch(void* const* d_in, const int* in_sizes, int n_in,
                              void* d_out, int out_size, void* d_ws, size_t ws_size,
                              hipStream_t stream)
{
  const int*   x   = (const int*)d_in[0];
  const float* tab = (const float*)d_in[1];
  const float* fW  = (const float*)d_in[2];
  const float* fU  = (const float*)d_in[3];
  const float* fb  = (const float*)d_in[4];
  const float* bW  = (const float*)d_in[5];
  const float* bU  = (const float*)d_in[6];
  const float* bb  = (const float*)d_in[7];
  const float* Wp  = (const float*)d_in[8];
  const float* bp  = (const float*)d_in[9];
  const float* Wn  = (const float*)d_in[10];
  const float* bn  = (const float*)d_in[11];
  float* out = (float*)d_out;
  char* ws = (char*)d_ws;

  int*  ctr   = (int*)(ws + OFF_CTR);
  bf16* h0f   = (bf16*)(ws + OFF_H0F);
  bf16* h0b   = (bf16*)(ws + OFF_H0B);
  bf16* h1f   = (bf16*)(ws + OFF_H1F);
  bf16* h1b   = (bf16*)(ws + OFF_H1B);
  bf16* xf    = (bf16*)(ws + OFF_XF);
  bf16* xb    = (bf16*)(ws + OFF_XB);
  bf16* fW0T  = (bf16*)(ws + OFF_FW0T);
  bf16* bW0T  = (bf16*)(ws + OFF_BW0T);
  float* pre0f = (float*)(ws + OFF_PRE0F);
  float* pre0b = (float*)(ws + OFF_PRE0B);
  bf16* WpT   = (bf16*)(ws + OFF_WPT);
  bf16* ctx   = (bf16*)(ws + OFF_CTX);
  unsigned char* mf = (unsigned char*)(ws + OFF_MF);
  unsigned char* mb = (unsigned char*)(ws + OFF_MB);

  hipMemsetAsync(ws, 0, ZERO_BYTES, stream);

  embed_kernel<<<dim3(127, 32), 256, 0, stream>>>(x, tab, xf, xb, mf, mb);

  transpose_to_bf16<<<dim3(16, 4),  256, 0, stream>>>(fW, fW0T, 256, 1024);
  transpose_to_bf16<<<dim3(16, 4),  256, 0, stream>>>(bW, bW0T, 256, 1024);
  transpose_to_bf16<<<dim3(500, 8), 256, 0, stream>>>(Wp, WpT, 512, 32000);

  gemm_bf16<<<dim3(32, 8), 256, 0, stream>>>(xf, fW0T, fb, pre0f, 4064, 1024, 256);
  gemm_bf16<<<dim3(32, 8), 256, 0, stream>>>(xb, bW0T, bb, pre0b, 4064, 1024, 256);

  recur_kernel<<<64, 512, 0, stream>>>(
      pre0f, pre0b,
      fU, bU,
      fW + 262144, fU + 262144, bW + 262144, bU + 262144,
      fb + 1024, bb + 1024,
      mf, mb, h0f, h0b, h1f, h1b, ctr);

  ctx_kernel<<<dim3(126, 32), 256, 0, stream>>>(h1f, h1b, ctx);

  gemm_bf16<<<dim3(32, 250), 256, 0, stream>>>(ctx, WpT, bp, out, 4032, 32000, 512);

  nsp_kernel<<<32, 256, 0, stream>>>(ctx, Wn, bn, out + (size_t)4032*32000);
}